// Round 2
// baseline (986.513 us; speedup 1.0000x reference)
//
#include <hip/hip_runtime.h>
#include <math.h>

#define NSAMP 4194304
#define LAYERS 256
#define SPT 8   // samples per thread (4 packed pairs)

typedef float f32x2 __attribute__((ext_vector_type(2)));

__device__ __forceinline__ f32x2 splat2(float v) { f32x2 r = {v, v}; return r; }
__device__ __forceinline__ f32x2 vfma2(f32x2 a, f32x2 b, f32x2 c) {
  return __builtin_elementwise_fma(a, b, c);
}

// ws float layout:
// [0]=f3000  [1]=cpar  [2]=bo_fold  [3..6]=wo_fold[0..3]
// [16 .. 16+8192)       W2: pre-splatted {w'',w''} pairs, pair idx = l*16+i*4+j
// [8208 .. 8208+2048)   B2: pre-splatted {b'',b''} pairs, pair idx = l*4+i
#define WS_W2 16
#define WS_B2 8208

__global__ void prep_kernel(
    const float* __restrict__ w_hidden, const float* __restrict__ b_hidden,
    const float* __restrict__ w_out,   const float* __restrict__ b_out,
    const float* __restrict__ a_param, const float* __restrict__ b_param,
    const float* __restrict__ c_param, const float* __restrict__ d_param,
    float* __restrict__ ws)
{
  const double TWO_PI = 6.283185307179586476925286766559;
  int idx = blockIdx.x * blockDim.x + threadIdx.x;
  float freqf = (float)exp((double)b_param[0]);   // f32(exp(b)) like reference
  float gf    = (float)((double)freqf * 30.0);    // f32(freq*30)
  float ampf  = (float)exp((double)a_param[0]);
  double scale = (double)gf / TWO_PI;             // W' scale (revolution units)
  double dd = (double)d_param[0];
  if (idx < 4096) {
    // W''[l][i][j] = amp * W' = amp * W * g / 2pi
    float wv = (float)((double)w_hidden[idx] * scale * (double)ampf);
    ws[WS_W2 + 2*idx]     = wv;
    ws[WS_W2 + 2*idx + 1] = wv;
  } else if (idx < 5120) {
    int bi = idx - 4096;
    int l = bi >> 2, i = bi & 3;
    double rs = 0.0;
    for (int j = 0; j < 4; ++j) rs += (double)w_hidden[l*16 + i*4 + j];
    // b'' = (g*b + c)/2pi + d * (g/2pi) * rowsum(W)
    double bv = ((double)gf * (double)b_hidden[bi] + (double)c_param[0]) / TWO_PI
              + dd * scale * rs;
    float b = (float)bv;
    ws[WS_B2 + 2*bi]     = b;
    ws[WS_B2 + 2*bi + 1] = b;
  } else if (idx == 5120) {
    ws[0] = (float)((double)freqf * 3000.0);      // f3000
    ws[1] = c_param[0];
    // out = sum_j (amp*w_out_j) * s_j + (b_out + d*sum_j w_out_j)
    double bo = (double)b_out[0]
              + dd * ((double)w_out[0] + (double)w_out[1] +
                      (double)w_out[2] + (double)w_out[3]);
    ws[2] = (float)bo;
    ws[3] = (float)((double)ampf * (double)w_out[0]);
    ws[4] = (float)((double)ampf * (double)w_out[1]);
    ws[5] = (float)((double)ampf * (double)w_out[2]);
    ws[6] = (float)((double)ampf * (double)w_out[3]);
  }
}

// accurate sin for the first layer (radians, |A| up to ~3e4):
// double Cody-Waite reduction + degree-13 Taylor (error << f32 ulp)
__device__ __forceinline__ float sin_first(float A) {
  double x = (double)A;
  double kd = rint(x * 0.31830988618379067154);   // 1/pi
  double r  = fma(-kd, 3.1415926535897931159979634685, x);
  r = fma(-kd, 1.2246467991473531772e-16, r);     // pi tail
  double r2 = r * r;
  double p = 1.6059043836821613e-10;              // 1/13!
  p = fma(r2, p, -2.5052108385441718775e-8);
  p = fma(r2, p,  2.7557319223985890653e-6);
  p = fma(r2, p, -1.9841269841269841270e-4);
  p = fma(r2, p,  8.3333333333333333333e-3);
  p = fma(r2, p, -1.6666666666666666667e-1);
  double s = fma(r2 * r, p, r);
  int ki = (int)kd;
  if (ki & 1) s = -s;
  return (float)s;
}

// packed sin(2*pi*z): reduce r = z - rint(z) in [-0.5,0.5], odd deg-15 Taylor
__device__ __forceinline__ f32x2 sin_rev2(f32x2 z) {
  f32x2 n;
  n.x = rintf(z.x);
  n.y = rintf(z.y);
  f32x2 r  = z - n;
  f32x2 r2 = r * r;
  f32x2 p  = splat2(-0.7181225f);                 // -(2pi)^15/15!
  p = vfma2(p, r2, splat2( 3.8199536f));
  p = vfma2(p, r2, splat2(-15.0946469f));
  p = vfma2(p, r2, splat2( 42.058693944897630f));
  p = vfma2(p, r2, splat2(-76.705859753061358f));
  p = vfma2(p, r2, splat2( 81.605249276075034f));
  p = vfma2(p, r2, splat2(-41.341702240399755f));
  p = vfma2(p, r2, splat2( 6.2831853071795865f)); // 2pi
  return r * p;
}

__global__ __launch_bounds__(256) void siren_main(
    const float* __restrict__ coords,
    const float* __restrict__ w_first, const float* __restrict__ b_first,
    const float* __restrict__ ws, float* __restrict__ out)
{
  const int tid = blockIdx.x * blockDim.x + threadIdx.x;   // 0 .. NSAMP/SPT-1
  const float f3000 = ws[0], cpar = ws[1];

  float c[SPT];
  const float4* cp4 = reinterpret_cast<const float4*>(coords) + tid * (SPT / 4);
#pragma unroll
  for (int q = 0; q < SPT / 4; ++q) {
    float4 v = cp4[q];
    c[4*q+0] = v.x; c[4*q+1] = v.y; c[4*q+2] = v.z; c[4*q+3] = v.w;
  }

  float wf[4], bf[4];
#pragma unroll
  for (int i = 0; i < 4; ++i) { wf[i] = w_first[i]; bf[i] = b_first[i]; }

  // sp[pair][neuron] = sin values (pre amp/d; those are folded into weights)
  f32x2 sp[SPT/2][4];
#pragma unroll
  for (int s = 0; s < SPT; ++s) {
#pragma unroll
    for (int i = 0; i < 4; ++i) {
      // replicate reference fp32 op order exactly for the argument:
      float t = __fmul_rn(c[s], wf[i]);
      t = __fadd_rn(t, bf[i]);
      float A = __fadd_rn(__fmul_rn(f3000, t), cpar);
      sp[s >> 1][i][s & 1] = sin_first(A);
    }
  }

  const f32x2* __restrict__ W2 = reinterpret_cast<const f32x2*>(ws + WS_W2);
  const f32x2* __restrict__ B2 = reinterpret_cast<const f32x2*>(ws + WS_B2);

  for (int l = 0; l < LAYERS; ++l) {
    f32x2 wv[16], bv[4];
#pragma unroll
    for (int k = 0; k < 16; ++k) wv[k] = W2[l * 16 + k];
#pragma unroll
    for (int i = 0; i < 4; ++i) bv[i] = B2[l * 4 + i];
#pragma unroll
    for (int p = 0; p < SPT/2; ++p) {
      f32x2 z[4];
#pragma unroll
      for (int i = 0; i < 4; ++i) {
        z[i] = vfma2(wv[i*4+0], sp[p][0], bv[i]);
#pragma unroll
        for (int j = 1; j < 4; ++j) z[i] = vfma2(wv[i*4+j], sp[p][j], z[i]);
      }
#pragma unroll
      for (int i = 0; i < 4; ++i) sp[p][i] = sin_rev2(z[i]);
    }
  }

  const f32x2 wo0 = splat2(ws[3]), wo1 = splat2(ws[4]);
  const f32x2 wo2 = splat2(ws[5]), wo3 = splat2(ws[6]);
  const f32x2 bo  = splat2(ws[2]);
  f32x2 o[SPT/2];
#pragma unroll
  for (int p = 0; p < SPT/2; ++p) {
    f32x2 acc = vfma2(wo0, sp[p][0], bo);
    acc = vfma2(wo1, sp[p][1], acc);
    acc = vfma2(wo2, sp[p][2], acc);
    acc = vfma2(wo3, sp[p][3], acc);
    o[p] = acc;
  }
  float4* op4 = reinterpret_cast<float4*>(out) + tid * (SPT / 4);
  float4 v0 = { o[0].x, o[0].y, o[1].x, o[1].y };
  float4 v1 = { o[2].x, o[2].y, o[3].x, o[3].y };
  op4[0] = v0;
  op4[1] = v1;
}

extern "C" void kernel_launch(void* const* d_in, const int* in_sizes, int n_in,
                              void* d_out, int out_size, void* d_ws, size_t ws_size,
                              hipStream_t stream) {
  const float* coords   = (const float*)d_in[0];
  const float* w_first  = (const float*)d_in[1];
  const float* b_first  = (const float*)d_in[2];
  const float* w_hidden = (const float*)d_in[3];
  const float* b_hidden = (const float*)d_in[4];
  const float* w_out    = (const float*)d_in[5];
  const float* b_out    = (const float*)d_in[6];
  const float* a_param  = (const float*)d_in[7];
  const float* b_param  = (const float*)d_in[8];
  const float* c_param  = (const float*)d_in[9];
  const float* d_param  = (const float*)d_in[10];
  float* ws   = (float*)d_ws;
  float* outp = (float*)d_out;

  prep_kernel<<<21, 256, 0, stream>>>(w_hidden, b_hidden, w_out, b_out,
                                      a_param, b_param, c_param, d_param, ws);

  const int threads = NSAMP / SPT;          // 524288
  siren_main<<<threads / 256, 256, 0, stream>>>(coords, w_first, b_first, ws, outp);
}

// Round 3
// 723.312 us; speedup vs baseline: 1.3639x; 1.3639x over previous
//
#include <hip/hip_runtime.h>
#include <math.h>

#define NSAMP 4194304
#define LAYERS 256
#define SPT 8   // samples per thread

// ws float layout:
// [0]=f3000  [1]=cpar  [2]=bo_fold  [3..6]=wo_fold[0..3]
// [16 + l*20 + 0..15]  W''[l][i][j] = amp * W * g / 2pi   (g = f32(freq)*30)
// [16 + l*20 + 16..19] b''[l][i]    = (g*b + c)/2pi + d*(g/2pi)*rowsum(W)
#define WS_W 16

__global__ void prep_kernel(
    const float* __restrict__ w_hidden, const float* __restrict__ b_hidden,
    const float* __restrict__ w_out,   const float* __restrict__ b_out,
    const float* __restrict__ a_param, const float* __restrict__ b_param,
    const float* __restrict__ c_param, const float* __restrict__ d_param,
    float* __restrict__ ws)
{
  const double TWO_PI = 6.283185307179586476925286766559;
  int idx = blockIdx.x * blockDim.x + threadIdx.x;
  float freqf = (float)exp((double)b_param[0]);   // f32(exp(b)) like reference
  float gf    = (float)((double)freqf * 30.0);    // f32(freq*30)
  float ampf  = (float)exp((double)a_param[0]);
  double scale = (double)gf / TWO_PI;             // revolution-unit W scale
  double dd = (double)d_param[0];
  if (idx < 4096) {
    int l = idx >> 4, r = idx & 15;
    float wv = (float)((double)w_hidden[idx] * scale * (double)ampf);
    ws[WS_W + l * 20 + r] = wv;
  } else if (idx < 5120) {
    int bi = idx - 4096;
    int l = bi >> 2, i = bi & 3;
    double rs = 0.0;
    for (int j = 0; j < 4; ++j) rs += (double)w_hidden[l*16 + i*4 + j];
    double bv = ((double)gf * (double)b_hidden[bi] + (double)c_param[0]) / TWO_PI
              + dd * scale * rs;
    ws[WS_W + l * 20 + 16 + i] = (float)bv;
  } else if (idx == 5120) {
    ws[0] = (float)((double)freqf * 3000.0);      // f3000
    ws[1] = c_param[0];
    double bo = (double)b_out[0]
              + dd * ((double)w_out[0] + (double)w_out[1] +
                      (double)w_out[2] + (double)w_out[3]);
    ws[2] = (float)bo;
    ws[3] = (float)((double)ampf * (double)w_out[0]);
    ws[4] = (float)((double)ampf * (double)w_out[1]);
    ws[5] = (float)((double)ampf * (double)w_out[2]);
    ws[6] = (float)((double)ampf * (double)w_out[3]);
  }
}

#if defined(__has_builtin)
#if __has_builtin(__builtin_amdgcn_sinf)
#define HAVE_SINF_BUILTIN 1
#endif
#endif

// hardware sin: input in revolutions, computes sin(2*pi*x)
__device__ __forceinline__ float vsin_rev(float x) {
#ifdef HAVE_SINF_BUILTIN
  return __builtin_amdgcn_sinf(x);
#else
  float r;
  asm("v_sin_f32 %0, %1" : "=v"(r) : "v"(x));
  return r;
#endif
}

// accurate sin for the first layer (radians, |A| up to ~3e4):
// double Cody-Waite reduction + degree-13 Taylor (error << f32 ulp)
__device__ __forceinline__ float sin_first(float A) {
  double x = (double)A;
  double kd = rint(x * 0.31830988618379067154);   // 1/pi
  double r  = fma(-kd, 3.1415926535897931159979634685, x);
  r = fma(-kd, 1.2246467991473531772e-16, r);     // pi tail
  double r2 = r * r;
  double p = 1.6059043836821613e-10;
  p = fma(r2, p, -2.5052108385441718775e-8);
  p = fma(r2, p,  2.7557319223985890653e-6);
  p = fma(r2, p, -1.9841269841269841270e-4);
  p = fma(r2, p,  8.3333333333333333333e-3);
  p = fma(r2, p, -1.6666666666666666667e-1);
  double s = fma(r2 * r, p, r);
  int ki = (int)kd;
  if (ki & 1) s = -s;
  return (float)s;
}

__global__ __launch_bounds__(256) void siren_main(
    const float* __restrict__ coords,
    const float* __restrict__ w_first, const float* __restrict__ b_first,
    const float* __restrict__ ws, float* __restrict__ out)
{
  const int tid = blockIdx.x * blockDim.x + threadIdx.x;   // 0 .. NSAMP/SPT-1
  const float f3000 = ws[0], cpar = ws[1];

  float c[SPT];
  const float4* cp4 = reinterpret_cast<const float4*>(coords) + tid * (SPT / 4);
#pragma unroll
  for (int q = 0; q < SPT / 4; ++q) {
    float4 v = cp4[q];
    c[4*q+0] = v.x; c[4*q+1] = v.y; c[4*q+2] = v.z; c[4*q+3] = v.w;
  }

  float wf[4], bf[4];
#pragma unroll
  for (int i = 0; i < 4; ++i) { wf[i] = w_first[i]; bf[i] = b_first[i]; }

  // sp[sample][neuron] = raw sin values (amp/d folded into downstream weights)
  float sp[SPT][4];
#pragma unroll
  for (int s = 0; s < SPT; ++s) {
#pragma unroll
    for (int i = 0; i < 4; ++i) {
      // replicate reference fp32 op order exactly for the argument:
      float t = __fmul_rn(c[s], wf[i]);
      t = __fadd_rn(t, bf[i]);
      float A = __fadd_rn(__fmul_rn(f3000, t), cpar);
      sp[s][i] = sin_first(A);
    }
  }

  const float* __restrict__ Wb = ws + WS_W;

  // one layer: z = W''*sp + b'' (revolutions), sp = sin(2*pi*z)
#define STEP(WREG)                                                      \
  {                                                                     \
    _Pragma("unroll")                                                   \
    for (int s = 0; s < SPT; ++s) {                                     \
      float z0 = fmaf(WREG[0],  sp[s][0], WREG[16]);                    \
      z0 = fmaf(WREG[1],  sp[s][1], z0);                                \
      z0 = fmaf(WREG[2],  sp[s][2], z0);                                \
      z0 = fmaf(WREG[3],  sp[s][3], z0);                                \
      float z1 = fmaf(WREG[4],  sp[s][0], WREG[17]);                    \
      z1 = fmaf(WREG[5],  sp[s][1], z1);                                \
      z1 = fmaf(WREG[6],  sp[s][2], z1);                                \
      z1 = fmaf(WREG[7],  sp[s][3], z1);                                \
      float z2 = fmaf(WREG[8],  sp[s][0], WREG[18]);                    \
      z2 = fmaf(WREG[9],  sp[s][1], z2);                                \
      z2 = fmaf(WREG[10], sp[s][2], z2);                                \
      z2 = fmaf(WREG[11], sp[s][3], z2);                                \
      float z3 = fmaf(WREG[12], sp[s][0], WREG[19]);                    \
      z3 = fmaf(WREG[13], sp[s][1], z3);                                \
      z3 = fmaf(WREG[14], sp[s][2], z3);                                \
      z3 = fmaf(WREG[15], sp[s][3], z3);                                \
      sp[s][0] = vsin_rev(z0);                                          \
      sp[s][1] = vsin_rev(z1);                                          \
      sp[s][2] = vsin_rev(z2);                                          \
      sp[s][3] = vsin_rev(z3);                                          \
    }                                                                   \
  }

  // double-buffered weight prefetch; named buffers keep indexing static
  float wA[20], wB[20];
#pragma unroll
  for (int k = 0; k < 20; ++k) wA[k] = Wb[k];

  for (int l = 0; l < LAYERS; l += 2) {
    const float* p1 = Wb + (l + 1) * 20;
#pragma unroll
    for (int k = 0; k < 20; ++k) wB[k] = p1[k];
    STEP(wA);                                   // layer l
    if (l + 2 < LAYERS) {
      const float* p2 = Wb + (l + 2) * 20;
#pragma unroll
      for (int k = 0; k < 20; ++k) wA[k] = p2[k];
    }
    STEP(wB);                                   // layer l+1
  }
#undef STEP

  const float wo0 = ws[3], wo1 = ws[4], wo2 = ws[5], wo3 = ws[6], bo = ws[2];
  float o[SPT];
#pragma unroll
  for (int s = 0; s < SPT; ++s) {
    float acc = fmaf(sp[s][0], wo0, bo);
    acc = fmaf(sp[s][1], wo1, acc);
    acc = fmaf(sp[s][2], wo2, acc);
    acc = fmaf(sp[s][3], wo3, acc);
    o[s] = acc;
  }
  float4* op4 = reinterpret_cast<float4*>(out) + tid * (SPT / 4);
  float4 v0 = { o[0], o[1], o[2], o[3] };
  float4 v1 = { o[4], o[5], o[6], o[7] };
  op4[0] = v0;
  op4[1] = v1;
}

extern "C" void kernel_launch(void* const* d_in, const int* in_sizes, int n_in,
                              void* d_out, int out_size, void* d_ws, size_t ws_size,
                              hipStream_t stream) {
  const float* coords   = (const float*)d_in[0];
  const float* w_first  = (const float*)d_in[1];
  const float* b_first  = (const float*)d_in[2];
  const float* w_hidden = (const float*)d_in[3];
  const float* b_hidden = (const float*)d_in[4];
  const float* w_out    = (const float*)d_in[5];
  const float* b_out    = (const float*)d_in[6];
  const float* a_param  = (const float*)d_in[7];
  const float* b_param  = (const float*)d_in[8];
  const float* c_param  = (const float*)d_in[9];
  const float* d_param  = (const float*)d_in[10];
  float* ws   = (float*)d_ws;
  float* outp = (float*)d_out;

  prep_kernel<<<21, 256, 0, stream>>>(w_hidden, b_hidden, w_out, b_out,
                                      a_param, b_param, c_param, d_param, ws);

  const int threads = NSAMP / SPT;          // 524288
  siren_main<<<threads / 256, 256, 0, stream>>>(coords, w_first, b_first, ws, outp);
}